// Round 11
// baseline (174.154 us; speedup 1.0000x reference)
//
#include <hip/hip_runtime.h>
#include <hip/hip_bf16.h>

// Problem constants (fixed by the reference's setup_inputs)
#define C_DIM 64
#define P_DIM 16
#define K_DIM 9            // K1*K1
#define INV2S 0.35355339059327373f  // 1/(2*sqrt(2))

// Z pair-table: Zp[n][i1][b0][p] = (Z[b0,i1], Z[b0+1,i1]) packed 2xbf16/dword
// row = 3*2*16 = 96 dwords = 384 B
#define ZP_ROW 96
// LDS staging stride for the pair table, in dwords (100%32=4 -> 2-way banks)
#define ZP_STRIDE 100
// shared floats: max(x-tile 64*68, z-stage 64*100) = max(4352, 6400)
#define SH_FLOATS 6400

// round-to-nearest-even f32 -> bf16 bits
__device__ __forceinline__ unsigned bf_bits(float x) {
    unsigned u = __float_as_uint(x);
    return (u + 0x7fffu + ((u >> 16) & 1u)) >> 16;
}
__device__ __forceinline__ float bf_lo(unsigned w) { return __uint_as_float(w << 16); }
__device__ __forceinline__ float bf_hi(unsigned w) { return __uint_as_float(w & 0xffff0000u); }

// ---------------------------------------------------------------------------
// Kernel 1: fused  (a) out bias-init for this block's 64 rows
//                  (b) poseb[n][p] = packed bf16 (a,b)
//                  (c) Zp pair table (bf16) from Z[n,p,k] = sum_c x[n,c]W[p,k,c]
// ---------------------------------------------------------------------------
__global__ __launch_bounds__(256) void z_gemm_kernel(const float* __restrict__ x,
                                                     const float* __restrict__ W,
                                                     const float* __restrict__ bias,
                                                     const float* __restrict__ pose,
                                                     float* __restrict__ out,
                                                     unsigned* __restrict__ Zp,
                                                     unsigned* __restrict__ poseb,
                                                     int N) {
    __shared__ float sh_raw[SH_FLOATS];
    float (*xs)[C_DIM + 4] = (float(*)[C_DIM + 4])sh_raw;   // [64][68]
    unsigned* zs = (unsigned*)sh_raw;                        // [64 * ZP_STRIDE]

    const int block_row = blockIdx.x * 64;
    const int tid = threadIdx.x;

    // (a) bias-init: 64 rows x 16 = 256 float4s
    {
        const float4 b4 = ((const float4*)bias)[tid & 3];
        const int o4 = block_row * 4 + tid;
        if (o4 < N * 4) ((float4*)out)[o4] = b4;
    }

    // (b) pose -> packed bf16, 1024 (r,p) pairs
    #pragma unroll
    for (int j = 0; j < 4; ++j) {
        int idx = j * 256 + tid;
        int gr = block_row + (idx >> 4);
        int pp = idx & 15;
        if (gr < N) {
            float2 ab = ((const float2*)pose)[(size_t)gr * P_DIM + pp];
            poseb[(size_t)gr * P_DIM + pp] = bf_bits(ab.x) | (bf_bits(ab.y) << 16);
        }
    }

    // stage x tile: 1024 float4s
    for (int i = tid; i < C_DIM * (C_DIM / 4); i += 256) {
        int r = i >> 4, c4 = i & 15;
        int gr = block_row + r;
        float4 v = make_float4(0.0f, 0.0f, 0.0f, 0.0f);
        if (gr < N) v = ((const float4*)x)[(size_t)gr * (C_DIM / 4) + c4];
        *(float4*)&xs[r][c4 * 4] = v;
    }
    __syncthreads();

    const int rg = tid & 15;   // rows rg, rg+16, rg+32, rg+48
    const int p  = tid >> 4;   // 0..15
    const int j0 = p * K_DIM;

    float acc[4][K_DIM];
    #pragma unroll
    for (int i = 0; i < 4; ++i)
        #pragma unroll
        for (int k = 0; k < K_DIM; ++k) acc[i][k] = 0.0f;

    const float4* W4 = (const float4*)W;
    #pragma unroll 4
    for (int cs = 0; cs < 16; ++cs) {
        float4 xv[4];
        #pragma unroll
        for (int i = 0; i < 4; ++i) xv[i] = *(const float4*)&xs[rg + 16 * i][cs * 4];
        #pragma unroll
        for (int k = 0; k < K_DIM; ++k) {
            float4 wv = W4[(size_t)(j0 + k) * (C_DIM / 4) + cs];
            #pragma unroll
            for (int i = 0; i < 4; ++i) {
                acc[i][k] = fmaf(xv[i].x, wv.x, acc[i][k]);
                acc[i][k] = fmaf(xv[i].y, wv.y, acc[i][k]);
                acc[i][k] = fmaf(xv[i].z, wv.z, acc[i][k]);
                acc[i][k] = fmaf(xv[i].w, wv.w, acc[i][k]);
            }
        }
    }
    __syncthreads();   // done reading xs; reuse LDS as zs

    // (c) stage pair table in LDS: zs[row][ (i1*2+b0)*16 + p ]
    #pragma unroll
    for (int i = 0; i < 4; ++i) {
        unsigned* zrow = &zs[(rg + 16 * i) * ZP_STRIDE + p];
        #pragma unroll
        for (int i1 = 0; i1 < 3; ++i1)
            #pragma unroll
            for (int b0 = 0; b0 < 2; ++b0)
                zrow[(i1 * 2 + b0) * 16] =
                    bf_bits(acc[i][b0 + 3 * i1]) | (bf_bits(acc[i][b0 + 1 + 3 * i1]) << 16);
    }
    __syncthreads();

    // coalesced write-out: 64 rows x 24 float4 = 1536 float4s
    const int nrow = min(64, N - block_row);
    float4* Zp4 = (float4*)Zp;
    const float4* zs4 = (const float4*)sh_raw;
    for (int i = tid; i < nrow * 24; i += 256) {
        int row = i / 24, q = i - row * 24;
        Zp4[(size_t)(block_row + row) * 24 + q] = zs4[row * (ZP_STRIDE / 4) + q];
    }
}

// ---------------------------------------------------------------------------
// Kernel 2: prep[e] = (d0, d1, r, c)
// ---------------------------------------------------------------------------
__global__ __launch_bounds__(256) void prep_kernel(const int* __restrict__ ei,
                                                   const float* __restrict__ pos,
                                                   float4* __restrict__ prep,
                                                   int E) {
    int i = blockIdx.x * 256 + threadIdx.x;
    if (i >= E) return;
    const int r = ei[i];
    const int c = ei[E + i];
    const float2 pc = ((const float2*)pos)[c];
    const float2 pr = ((const float2*)pos)[r];
    prep[i] = make_float4((pc.x - pr.x) * INV2S, (pc.y - pr.y) * INV2S,
                          __int_as_float(r), __int_as_float(c));
}

// ---------------------------------------------------------------------------
// Kernel 3: edge messages + scatter-add.
// thread-slot = (eg, p); 16 lanes share an edge; 4 edges per slot.
// Per (e,p): 1 broadcast prep load + 1 poseb dword + 2 Zp dwords + 1 atomic.
// ---------------------------------------------------------------------------
#define EILP 4
__global__ __launch_bounds__(256) void edge_kernel(const float4* __restrict__ prep,
                                                   const unsigned* __restrict__ poseb,
                                                   const unsigned* __restrict__ Zp,
                                                   float* __restrict__ out,
                                                   int E) {
    const int p  = threadIdx.x & 15;
    const int eg = threadIdx.x >> 4;
    const int e0 = blockIdx.x * (16 * EILP) + eg;

    float4 ed[EILP];
    bool valid[EILP];
    #pragma unroll
    for (int it = 0; it < EILP; ++it) {
        int e = e0 + it * 16;
        valid[it] = (e < E);
        ed[it] = prep[valid[it] ? e : 0];
    }

    unsigned pw[EILP];
    #pragma unroll
    for (int it = 0; it < EILP; ++it) {
        int r = __float_as_int(ed[it].z);
        pw[it] = poseb[(size_t)r * P_DIM + p];
    }

    unsigned pa[EILP], pb[EILP];
    float f0[EILP], f1[EILP];
    #pragma unroll
    for (int it = 0; it < EILP; ++it) {
        const float a = bf_lo(pw[it]);
        const float b = bf_hi(pw[it]);
        const float d0 = ed[it].x, d1 = ed[it].y;
        const float p0 = fmaf(a, d0, fmaf(-b, d1, 0.5f));
        const float p1 = fmaf(b, d0, fmaf( a, d1, 0.5f));

        const float v0 = fminf(fmaxf(p0, 0.0f) * 2.0f, 1.9999999f);
        const float v1 = fminf(fmaxf(p1, 0.0f) * 2.0f, 1.9999999f);
        const float lo0 = floorf(v0);
        const float lo1 = floorf(v1);
        f0[it] = v0 - lo0;
        f1[it] = v1 - lo1;
        const int b0 = (int)lo0;        // 0 or 1
        const int b1 = (int)lo1;        // 0 or 1

        const int c = __float_as_int(ed[it].w);
        const unsigned* Zr = Zp + (size_t)c * ZP_ROW + b0 * 16 + p + b1 * 32;
        pa[it] = Zr[0];     // (Z[b0,b1],   Z[b0+1,b1])
        pb[it] = Zr[32];    // (Z[b0,b1+1], Z[b0+1,b1+1])
    }

    #pragma unroll
    for (int it = 0; it < EILP; ++it) {
        const float za = bf_lo(pa[it]), zb = bf_hi(pa[it]);
        const float zc = bf_lo(pb[it]), zd = bf_hi(pb[it]);
        const float mlo = fmaf(f0[it], zb - za, za);
        const float mhi = fmaf(f0[it], zd - zc, zc);
        const float m   = fmaf(f1[it], mhi - mlo, mlo);
        const int r = __float_as_int(ed[it].z);
        if (valid[it]) atomicAdd(&out[(size_t)r * P_DIM + p], m);
    }
}

// ---------------------------------------------------------------------------
extern "C" void kernel_launch(void* const* d_in, const int* in_sizes, int n_in,
                              void* d_out, int out_size, void* d_ws, size_t ws_size,
                              hipStream_t stream) {
    const float* x    = (const float*)d_in[0];
    const float* pos  = (const float*)d_in[1];
    const float* pose = (const float*)d_in[2];
    const float* W    = (const float*)d_in[3];
    const float* bias = (const float*)d_in[4];
    const int*   ei   = (const int*)d_in[5];

    const int N = in_sizes[0] / C_DIM;   // 50000
    const int E = in_sizes[5] / 2;       // 800000

    float* out = (float*)d_out;

    // workspace: Zp 19.2 MB | poseb 3.2 MB | prep 12.8 MB  (= 35.2 MB total)
    const size_t zp_bytes = (size_t)N * ZP_ROW * sizeof(unsigned);
    const size_t pb_bytes = (size_t)N * P_DIM * sizeof(unsigned);
    unsigned* Zp    = (unsigned*)d_ws;
    unsigned* poseb = (unsigned*)((char*)d_ws + zp_bytes);
    float4*   prep  = (float4*)((char*)d_ws + zp_bytes + pb_bytes);

    z_gemm_kernel<<<(N + 63) / 64, 256, 0, stream>>>(x, W, bias, pose, out, Zp, poseb, N);
    prep_kernel<<<(E + 255) / 256, 256, 0, stream>>>(ei, pos, prep, E);
    edge_kernel<<<(E + 16 * EILP - 1) / (16 * EILP), 256, 0, stream>>>(prep, poseb, Zp, out, E);
}

// Round 12
// 164.870 us; speedup vs baseline: 1.0563x; 1.0563x over previous
//
#include <hip/hip_runtime.h>
#include <hip/hip_bf16.h>

// Problem constants (fixed by the reference's setup_inputs)
#define C_DIM 64
#define P_DIM 16
#define K_DIM 9            // K1*K1
#define INV2S 0.35355339059327373f  // 1/(2*sqrt(2))

// Z pair-table: Zp[n][i1][b0][p] = (Z[b0,i1], Z[b0+1,i1]) packed 2xbf16/dword
// row = 3*2*16 = 96 dwords = 384 B
#define ZP_ROW 96
// LDS staging stride for the pair table, in dwords (100%32=4 -> 2-way banks)
#define ZP_STRIDE 100
// shared floats: max(x-tile 64*68, z-stage 64*100) = max(4352, 6400)
#define SH_FLOATS 6400

// round-to-nearest-even f32 -> bf16 bits
__device__ __forceinline__ unsigned bf_bits(float x) {
    unsigned u = __float_as_uint(x);
    return (u + 0x7fffu + ((u >> 16) & 1u)) >> 16;
}
__device__ __forceinline__ float bf_lo(unsigned w) { return __uint_as_float(w << 16); }
__device__ __forceinline__ float bf_hi(unsigned w) { return __uint_as_float(w & 0xffff0000u); }

// ---------------------------------------------------------------------------
// Kernel 1: fused  (a) out bias-init for this block's 64 rows
//                  (b) poseb[n][p] = packed bf16 (a,b)
//                  (c) Zp pair table (bf16) from Z[n,p,k] = sum_c x[n,c]W[p,k,c]
// ---------------------------------------------------------------------------
__global__ __launch_bounds__(256) void z_gemm_kernel(const float* __restrict__ x,
                                                     const float* __restrict__ W,
                                                     const float* __restrict__ bias,
                                                     const float* __restrict__ pose,
                                                     float* __restrict__ out,
                                                     unsigned* __restrict__ Zp,
                                                     unsigned* __restrict__ poseb,
                                                     int N) {
    __shared__ float sh_raw[SH_FLOATS];
    float (*xs)[C_DIM + 4] = (float(*)[C_DIM + 4])sh_raw;   // [64][68]
    unsigned* zs = (unsigned*)sh_raw;                        // [64 * ZP_STRIDE]

    const int block_row = blockIdx.x * 64;
    const int tid = threadIdx.x;

    // (a) bias-init: 64 rows x 16 = 256 float4s
    {
        const float4 b4 = ((const float4*)bias)[tid & 3];
        const int o4 = block_row * 4 + tid;
        if (o4 < N * 4) ((float4*)out)[o4] = b4;
    }

    // (b) pose -> packed bf16, 1024 (r,p) pairs
    #pragma unroll
    for (int j = 0; j < 4; ++j) {
        int idx = j * 256 + tid;
        int gr = block_row + (idx >> 4);
        int pp = idx & 15;
        if (gr < N) {
            float2 ab = ((const float2*)pose)[(size_t)gr * P_DIM + pp];
            poseb[(size_t)gr * P_DIM + pp] = bf_bits(ab.x) | (bf_bits(ab.y) << 16);
        }
    }

    // stage x tile: 1024 float4s
    for (int i = tid; i < C_DIM * (C_DIM / 4); i += 256) {
        int r = i >> 4, c4 = i & 15;
        int gr = block_row + r;
        float4 v = make_float4(0.0f, 0.0f, 0.0f, 0.0f);
        if (gr < N) v = ((const float4*)x)[(size_t)gr * (C_DIM / 4) + c4];
        *(float4*)&xs[r][c4 * 4] = v;
    }
    __syncthreads();

    const int rg = tid & 15;   // rows rg, rg+16, rg+32, rg+48
    const int p  = tid >> 4;   // 0..15
    const int j0 = p * K_DIM;

    float acc[4][K_DIM];
    #pragma unroll
    for (int i = 0; i < 4; ++i)
        #pragma unroll
        for (int k = 0; k < K_DIM; ++k) acc[i][k] = 0.0f;

    const float4* W4 = (const float4*)W;
    #pragma unroll 4
    for (int cs = 0; cs < 16; ++cs) {
        float4 xv[4];
        #pragma unroll
        for (int i = 0; i < 4; ++i) xv[i] = *(const float4*)&xs[rg + 16 * i][cs * 4];
        #pragma unroll
        for (int k = 0; k < K_DIM; ++k) {
            float4 wv = W4[(size_t)(j0 + k) * (C_DIM / 4) + cs];
            #pragma unroll
            for (int i = 0; i < 4; ++i) {
                acc[i][k] = fmaf(xv[i].x, wv.x, acc[i][k]);
                acc[i][k] = fmaf(xv[i].y, wv.y, acc[i][k]);
                acc[i][k] = fmaf(xv[i].z, wv.z, acc[i][k]);
                acc[i][k] = fmaf(xv[i].w, wv.w, acc[i][k]);
            }
        }
    }
    __syncthreads();   // done reading xs; reuse LDS as zs

    // (c) stage pair table in LDS: zs[row][ (i1*2+b0)*16 + p ]
    #pragma unroll
    for (int i = 0; i < 4; ++i) {
        unsigned* zrow = &zs[(rg + 16 * i) * ZP_STRIDE + p];
        #pragma unroll
        for (int i1 = 0; i1 < 3; ++i1)
            #pragma unroll
            for (int b0 = 0; b0 < 2; ++b0)
                zrow[(i1 * 2 + b0) * 16] =
                    bf_bits(acc[i][b0 + 3 * i1]) | (bf_bits(acc[i][b0 + 1 + 3 * i1]) << 16);
    }
    __syncthreads();

    // coalesced write-out: 64 rows x 24 float4 = 1536 float4s
    const int nrow = min(64, N - block_row);
    float4* Zp4 = (float4*)Zp;
    const float4* zs4 = (const float4*)sh_raw;
    for (int i = tid; i < nrow * 24; i += 256) {
        int row = i / 24, q = i - row * 24;
        Zp4[(size_t)(block_row + row) * 24 + q] = zs4[row * (ZP_STRIDE / 4) + q];
    }
}

// ---------------------------------------------------------------------------
// Kernel 2: edge messages + scatter-add (unsorted).
// thread-slot = (eg, p); 16 lanes share an edge; 4 edges per slot.
// Per (e,p): 2 ei + 2 pos broadcast loads + 1 poseb dword + 2 Zp dwords + atomic.
// ---------------------------------------------------------------------------
#define EILP 4
__global__ __launch_bounds__(256) void edge_kernel(const int* __restrict__ ei,
                                                   const float* __restrict__ pos,
                                                   const unsigned* __restrict__ poseb,
                                                   const unsigned* __restrict__ Zp,
                                                   float* __restrict__ out,
                                                   int E) {
    const int p  = threadIdx.x & 15;
    const int eg = threadIdx.x >> 4;
    const int e0 = blockIdx.x * (16 * EILP) + eg;

    int  r[EILP], c[EILP];
    bool valid[EILP];
    #pragma unroll
    for (int it = 0; it < EILP; ++it) {
        int e = e0 + it * 16;
        valid[it] = (e < E);
        int ec = valid[it] ? e : 0;
        r[it] = ei[ec];
        c[it] = ei[E + ec];
    }

    float d0[EILP], d1[EILP];
    #pragma unroll
    for (int it = 0; it < EILP; ++it) {
        const float2 pc = ((const float2*)pos)[c[it]];
        const float2 pr = ((const float2*)pos)[r[it]];
        d0[it] = (pc.x - pr.x) * INV2S;
        d1[it] = (pc.y - pr.y) * INV2S;
    }

    unsigned pw[EILP];
    #pragma unroll
    for (int it = 0; it < EILP; ++it)
        pw[it] = poseb[(size_t)r[it] * P_DIM + p];

    unsigned pa[EILP], pb[EILP];
    float f0[EILP], f1[EILP];
    #pragma unroll
    for (int it = 0; it < EILP; ++it) {
        const float a = bf_lo(pw[it]);
        const float b = bf_hi(pw[it]);
        const float p0 = fmaf(a, d0[it], fmaf(-b, d1[it], 0.5f));
        const float p1 = fmaf(b, d0[it], fmaf( a, d1[it], 0.5f));

        const float v0 = fminf(fmaxf(p0, 0.0f) * 2.0f, 1.9999999f);
        const float v1 = fminf(fmaxf(p1, 0.0f) * 2.0f, 1.9999999f);
        const float lo0 = floorf(v0);
        const float lo1 = floorf(v1);
        f0[it] = v0 - lo0;
        f1[it] = v1 - lo1;
        const int b0 = (int)lo0;        // 0 or 1
        const int b1 = (int)lo1;        // 0 or 1

        const unsigned* Zr = Zp + (size_t)c[it] * ZP_ROW + b1 * 32 + b0 * 16 + p;
        pa[it] = Zr[0];     // (Z[b0,b1],   Z[b0+1,b1])
        pb[it] = Zr[32];    // (Z[b0,b1+1], Z[b0+1,b1+1])
    }

    #pragma unroll
    for (int it = 0; it < EILP; ++it) {
        const float za = bf_lo(pa[it]), zb = bf_hi(pa[it]);
        const float zc = bf_lo(pb[it]), zd = bf_hi(pb[it]);
        const float mlo = fmaf(f0[it], zb - za, za);
        const float mhi = fmaf(f0[it], zd - zc, zc);
        const float m   = fmaf(f1[it], mhi - mlo, mlo);
        if (valid[it]) atomicAdd(&out[(size_t)r[it] * P_DIM + p], m);
    }
}

// ---------------------------------------------------------------------------
extern "C" void kernel_launch(void* const* d_in, const int* in_sizes, int n_in,
                              void* d_out, int out_size, void* d_ws, size_t ws_size,
                              hipStream_t stream) {
    const float* x    = (const float*)d_in[0];
    const float* pos  = (const float*)d_in[1];
    const float* pose = (const float*)d_in[2];
    const float* W    = (const float*)d_in[3];
    const float* bias = (const float*)d_in[4];
    const int*   ei   = (const int*)d_in[5];

    const int N = in_sizes[0] / C_DIM;   // 50000
    const int E = in_sizes[5] / 2;       // 800000

    float* out = (float*)d_out;

    // workspace: Zp 19.2 MB | poseb 3.2 MB
    const size_t zp_bytes = (size_t)N * ZP_ROW * sizeof(unsigned);
    unsigned* Zp    = (unsigned*)d_ws;
    unsigned* poseb = (unsigned*)((char*)d_ws + zp_bytes);

    z_gemm_kernel<<<(N + 63) / 64, 256, 0, stream>>>(x, W, bias, pose, out, Zp, poseb, N);
    edge_kernel<<<(E + 16 * EILP - 1) / (16 * EILP), 256, 0, stream>>>(ei, pos, poseb, Zp, out, E);
}